// Round 1
// 624.379 us; speedup vs baseline: 1.1655x; 1.1655x over previous
//
#include <hip/hip_runtime.h>
#include <cstdint>

#define BB 64
#define SS 512
#define HH 512
#define EE 512
#define BSH (BB*SS*HH)

typedef _Float16 f16x8 __attribute__((ext_vector_type(8)));
typedef float    f32x4 __attribute__((ext_vector_type(4)));
typedef int      iv4   __attribute__((ext_vector_type(4)));
typedef unsigned long long u64;

__device__ __forceinline__ float tanh_fast(float x) {
    float e = __expf(2.0f * x);
    return 1.0f - 2.0f / (e + 1.0f);
}
__device__ __forceinline__ f16x8 pack8(float4 u, float4 v) {
    f16x8 h;
    h[0] = (_Float16)u.x; h[1] = (_Float16)u.y;
    h[2] = (_Float16)u.z; h[3] = (_Float16)u.w;
    h[4] = (_Float16)v.x; h[5] = (_Float16)v.y;
    h[6] = (_Float16)v.z; h[7] = (_Float16)v.w;
    return h;
}

// W scale: |W| <= 1/sqrt(512); map to [-127,127]
#define SW (127.0f * 22.627416997969522f)

__device__ __forceinline__ int quanw(float x) {
    return (int)rintf(fminf(fmaxf(x * SW, -127.0f), 127.0f));
}
__device__ __forceinline__ int packw4(float4 f) {
    int q0 = quanw(f.x), q1 = quanw(f.y), q2 = quanw(f.z), q3 = quanw(f.w);
    return (q0 & 255) | ((q1 & 255) << 8) | ((q2 & 255) << 16) | (q3 << 24);
}

// ---------------- Phase 1 (unchanged): xp = W_ih @ emb[idx] + b_ih + b_hh
__global__ __launch_bounds__(256, 3) void phase1(
    const int* __restrict__ idx, const float* __restrict__ emb,
    const float* __restrict__ Wih, const float* __restrict__ bih,
    const float* __restrict__ bhh, float* __restrict__ out) {
    __shared__ __align__(16) _Float16 Al[128 * 72];
    __shared__ __align__(16) _Float16 Bl[128 * 72];

    const int tid  = threadIdx.x;
    const int m0   = (blockIdx.x >> 2) * 128;
    const int n0   = (blockIdx.x & 3) * 128;
    const int wv   = tid >> 6;
    const int lane = tid & 63;
    const int n    = lane & 15;
    const int quad = lane >> 4;
    const int mw   = wv >> 1;
    const int nw   = wv & 1;

    const int sr = tid >> 1;
    const int kh = (tid & 1) * 32;
    const int rowidx = idx[m0 + sr];
    const float* ap = emb + (size_t)rowidx * EE + kh;
    const float* bp = Wih + (size_t)(n0 + sr) * EE + kh;

    f32x4 acc[4][4];
#pragma unroll
    for (int a = 0; a < 4; ++a)
#pragma unroll
        for (int c = 0; c < 4; ++c) acc[a][c] = (f32x4){0.f, 0.f, 0.f, 0.f};

    for (int kc = 0; kc < 8; ++kc) {
#pragma unroll
        for (int q = 0; q < 4; ++q) {
            float4 u = *(const float4*)(ap + kc * 64 + q * 8);
            float4 v = *(const float4*)(ap + kc * 64 + q * 8 + 4);
            *(f16x8*)&Al[sr * 72 + kh + q * 8] = pack8(u, v);
        }
#pragma unroll
        for (int q = 0; q < 4; ++q) {
            float4 u = *(const float4*)(bp + kc * 64 + q * 8);
            float4 v = *(const float4*)(bp + kc * 64 + q * 8 + 4);
            *(f16x8*)&Bl[sr * 72 + kh + q * 8] = pack8(u, v);
        }
        __syncthreads();

#pragma unroll
        for (int kk = 0; kk < 2; ++kk) {
            f16x8 bfr[4];
#pragma unroll
            for (int nb = 0; nb < 4; ++nb)
                bfr[nb] = *(const f16x8*)&Bl[(nw * 64 + nb * 16 + n) * 72 + kk * 32 + quad * 8];
#pragma unroll
            for (int mb = 0; mb < 4; ++mb) {
                f16x8 afr = *(const f16x8*)&Al[(mw * 64 + mb * 16 + n) * 72 + kk * 32 + quad * 8];
#pragma unroll
                for (int nb = 0; nb < 4; ++nb)
                    acc[mb][nb] = __builtin_amdgcn_mfma_f32_16x16x32_f16(
                        afr, bfr[nb], acc[mb][nb], 0, 0, 0);
            }
        }
        __syncthreads();
    }

    int   cc[4];
    float bv[4];
#pragma unroll
    for (int nb = 0; nb < 4; ++nb) {
        cc[nb] = n0 + nw * 64 + nb * 16 + n;
        bv[nb] = bih[cc[nb]] + bhh[cc[nb]];
    }
#pragma unroll
    for (int mb = 0; mb < 4; ++mb) {
        int rowg = m0 + mw * 64 + mb * 16 + quad * 4;
#pragma unroll
        for (int nb = 0; nb < 4; ++nb) {
#pragma unroll
            for (int i = 0; i < 4; ++i)
                out[(size_t)(rowg + i) * HH + cc[nb]] = acc[mb][nb][i] + bv[nb];
        }
    }
}

// ---------------- Phase 2 v2: int8 MFMA recurrence, 32 WGs x 2 batches.
// Key changes vs v1:
//  * B-fragment was ALREADY batch-replicated across all 16 MFMA columns
//    ((n&1) read base) -> every lane's accumulators are valid. Remap the
//    epilogue (lane n -> batch n&1, tile (n>>1)&3, reg-pair n>>3) and
//    select in registers (v_cndmask) -- kills the cscr LDS round-trip
//    (~300 cyc/step serial).
//  * Raw `s_waitcnt lgkmcnt(0); s_barrier` instead of __syncthreads():
//    no per-step vmcnt(0) drain, so the HBM xp prefetch + out-store ack
//    leave the critical path. Loads are issued before stores in the body,
//    so the compiler's counted vmcnt wait for xp never drains stores.
//  * 2x unrolled ping-pong (no `cur` pointer selects, clean xp register
//    rotation); depth-2 xp prefetch.
//  * launch_bounds(512,1): 32 WGs on 256 CUs -> 1 block/CU is free;
//    relaxes the 128-VGPR cap.
// Matrix floor: 256 mfma_i32_16x16x64_i8/WG/step x ~5.1 cyc = ~1306 cyc;
// target ~1700 cyc/step total.
__global__ __launch_bounds__(512, 1) void phase2(
    const float* __restrict__ Whh, float* __restrict__ out) {
    __shared__ __align__(16) unsigned char himg[2][1024];  // ping-pong i8 h, [kb][col2][k64]

    const int tid  = threadIdx.x;
    const int g    = blockIdx.x;        // batches 2g, 2g+1
    const int wv   = tid >> 6;          // 0..7: W rows wv*64..+63
    const int lane = tid & 63;
    const int n    = lane & 15;
    const int quad = lane >> 4;

    // A-fragments (i8, 16x16x64): A[m=lane&15][k=quad*16+j], j=0..15.
    iv4 areg[4][8];                     // 128 regs
#pragma unroll
    for (int mb = 0; mb < 4; ++mb) {
        const float* wr = Whh + (size_t)(wv * 64 + mb * 16 + n) * HH + quad * 16;
#pragma unroll
        for (int kb = 0; kb < 8; ++kb) {
            const float4* p = (const float4*)(wr + kb * 64);
            iv4 v;
            v[0] = packw4(p[0]);
            v[1] = packw4(p[1]);
            v[2] = packw4(p[2]);
            v[3] = packw4(p[3]);
            areg[mb][kb] = v;
        }
    }
    if (tid < 128) ((u64*)himg[0])[tid] = 0;   // h0 = 0 (1 KB)
    __syncthreads();

    // Epilogue mapping: lane n -> batch bl=n&1, mb tile mbl=(n>>1)&3,
    // reg-pair ip=n>>3; rows r0,r0+1. Bijective over the wave's 64 rows
    // x 2 batches (D[r=quad*4+i][c=n], col c holds batch c&1 because the
    // B-frag replicates the two h vectors across column parity).
    const int  bl  = n & 1;
    const int  mbl = (n >> 1) & 3;
    const int  ip  = (n >> 3) & 1;
    const bool sb0 = ((n >> 1) & 1) != 0;   // low bit of mbl
    const bool sb1 = ((n >> 2) & 1) != 0;   // high bit of mbl
    const int  r0  = wv * 64 + mbl * 16 + quad * 4 + ip * 2;
    const int  b   = g * 2 + bl;
    float* obase = out + (size_t)b * (SS * HH) + r0;
    // h image write: [kb=wv][col=bl][klocal=r0&63], u16 (rows r0,r0+1)
    const int hwb = wv * 128 + bl * 64 + (mbl * 16 + quad * 4 + ip * 2);
    // B-frag read base: [kb][col=n&1][k=quad*16+j]
    const unsigned char* hbR0 = himg[0] + (n & 1) * 64 + quad * 16;
    const unsigned char* hbR1 = himg[1] + (n & 1) * 64 + quad * 16;
    unsigned char* hwW0 = himg[1] + hwb;   // step reads himg[0] -> writes himg[1]
    unsigned char* hwW1 = himg[0] + hwb;

    const float inv = 1.0f / (SW * 127.0f);

    float2 xp_c = *(const float2*)obase;
    float2 xp_n = *(const float2*)(obase + HH);
    float hl0 = 0.f, hl1 = 0.f;

#define RNN_STEP(T, HBR, HWW)                                                  \
    {                                                                          \
        int tl = (T) + 2; tl = tl < SS ? tl : (SS - 1);                        \
        float2 xp_f = *(const float2*)(obase + (size_t)tl * HH);               \
        iv4 acc0 = (iv4){0,0,0,0}, acc1 = (iv4){0,0,0,0};                      \
        iv4 acc2 = (iv4){0,0,0,0}, acc3 = (iv4){0,0,0,0};                      \
        _Pragma("unroll")                                                      \
        for (int kb = 0; kb < 8; ++kb) {                                       \
            iv4 bfr = *(const iv4*)((HBR) + (kb << 7));                        \
            acc0 = __builtin_amdgcn_mfma_i32_16x16x64_i8(areg[0][kb], bfr, acc0, 0, 0, 0); \
            acc1 = __builtin_amdgcn_mfma_i32_16x16x64_i8(areg[1][kb], bfr, acc1, 0, 0, 0); \
            acc2 = __builtin_amdgcn_mfma_i32_16x16x64_i8(areg[2][kb], bfr, acc2, 0, 0, 0); \
            acc3 = __builtin_amdgcn_mfma_i32_16x16x64_i8(areg[3][kb], bfr, acc3, 0, 0, 0); \
        }                                                                      \
        iv4 sa = sb0 ? acc1 : acc0;                                            \
        iv4 sc = sb0 ? acc3 : acc2;                                            \
        iv4 s  = sb1 ? sc : sa;                                                \
        int zx = ip ? s[2] : s[0];                                             \
        int zy = ip ? s[3] : s[1];                                             \
        float h0 = tanh_fast((float)zx * inv + xp_c.x);                        \
        float h1 = tanh_fast((float)zy * inv + xp_c.y);                        \
        int q0 = (int)rintf(h0 * 127.0f);                                      \
        int q1 = (int)rintf(h1 * 127.0f);                                      \
        *(unsigned short*)(HWW) =                                              \
            (unsigned short)((q0 & 255) | ((q1 & 255) << 8));                  \
        *(float2*)(obase + (size_t)(T) * HH) = make_float2(h0, h1);            \
        hl0 = h0; hl1 = h1;                                                    \
        __asm__ volatile("s_waitcnt lgkmcnt(0)\n\ts_barrier" ::: "memory");    \
        xp_c = xp_n; xp_n = xp_f;                                              \
    }

    for (int t = 0; t < SS; t += 2) {
        RNN_STEP(t,     hbR0, hwW0);
        RNN_STEP(t + 1, hbR1, hwW1);
    }
#undef RNN_STEP

    // final hidden state
    *(float2*)(out + BSH + (size_t)b * HH + r0) = make_float2(hl0, hl1);
}

extern "C" void kernel_launch(void* const* d_in, const int* in_sizes, int n_in,
                              void* d_out, int out_size, void* d_ws, size_t ws_size,
                              hipStream_t stream) {
    const int*   idx = (const int*)d_in[0];
    const float* emb = (const float*)d_in[1];
    const float* Wih = (const float*)d_in[2];
    const float* Whh = (const float*)d_in[3];
    const float* bih = (const float*)d_in[4];
    const float* bhh = (const float*)d_in[5];
    float* out = (float*)d_out;

    phase1<<<dim3(1024), dim3(256), 0, stream>>>(idx, emb, Wih, bih, bhh, out);
    phase2<<<dim3(32), dim3(512), 0, stream>>>(Whh, out);
}

// Round 3
// 568.616 us; speedup vs baseline: 1.2798x; 1.0981x over previous
//
#include <hip/hip_runtime.h>
#include <cstdint>

#define BB 64
#define SS 512
#define HH 512
#define EE 512
#define BSH (BB*SS*HH)

typedef _Float16 f16x8 __attribute__((ext_vector_type(8)));
typedef float    f32x4 __attribute__((ext_vector_type(4)));
typedef int      iv4   __attribute__((ext_vector_type(4)));
typedef unsigned long long u64;

__device__ __forceinline__ f16x8 pack8(float4 u, float4 v) {
    f16x8 h;
    h[0] = (_Float16)u.x; h[1] = (_Float16)u.y;
    h[2] = (_Float16)u.z; h[3] = (_Float16)u.w;
    h[4] = (_Float16)v.x; h[5] = (_Float16)v.y;
    h[6] = (_Float16)v.z; h[7] = (_Float16)v.w;
    return h;
}

// W scale: |W| <= 1/sqrt(512); map to [-127,127]
#define SW (127.0f * 22.627416997969522f)

__device__ __forceinline__ int quanw(float x) {
    return (int)rintf(fminf(fmaxf(x * SW, -127.0f), 127.0f));
}
__device__ __forceinline__ int packw4(float4 f) {
    int q0 = quanw(f.x), q1 = quanw(f.y), q2 = quanw(f.z), q3 = quanw(f.w);
    return (q0 & 255) | ((q1 & 255) << 8) | ((q2 & 255) << 16) | (q3 << 24);
}

// ---------------- prep: f32->f16 pre-pass into workspace.
// a16[m][e] = (f16)emb[idx[m]][e]  (32768x512, 32 MB)
// b16       = (f16)Wih             (512x512, 0.5 MB)
// Bit-identical conversions to the in-kernel pack8 -> absmax unchanged.
__global__ __launch_bounds__(256) void prep(
    const int* __restrict__ idx, const float* __restrict__ emb,
    const float* __restrict__ Wih, _Float16* __restrict__ a16,
    _Float16* __restrict__ b16) {
    const int bid = blockIdx.x, tid = threadIdx.x;
    if (bid < 8192) {
        int e = bid * 2048 + tid * 8;          // element into a16
        int m = e >> 9, c = e & 511;
        int gi = idx[m];
        const float* s = emb + (size_t)gi * EE + c;
        float4 u = *(const float4*)s, v = *(const float4*)(s + 4);
        *(f16x8*)(a16 + e) = pack8(u, v);
    } else {
        int e = (bid - 8192) * 2048 + tid * 8;
        float4 u = *(const float4*)(Wih + e), v = *(const float4*)(Wih + e + 4);
        *(f16x8*)(b16 + e) = pack8(u, v);
    }
}

// ---------------- Phase 1 fast path: f16 inputs (pre-converted).
// Staging is pure {16B load -> ds_write_b128}: no cvt VALU, half the bytes.
__global__ __launch_bounds__(256, 3) void phase1h(
    const _Float16* __restrict__ a16, const _Float16* __restrict__ b16,
    const float* __restrict__ bih, const float* __restrict__ bhh,
    float* __restrict__ out) {
    __shared__ __align__(16) _Float16 Al[128 * 72];
    __shared__ __align__(16) _Float16 Bl[128 * 72];

    const int tid  = threadIdx.x;
    const int m0   = (blockIdx.x >> 2) * 128;
    const int n0   = (blockIdx.x & 3) * 128;
    const int wv   = tid >> 6;
    const int lane = tid & 63;
    const int n    = lane & 15;
    const int quad = lane >> 4;
    const int mw   = wv >> 1;
    const int nw   = wv & 1;

    const int sr = tid >> 1;
    const int kh = (tid & 1) * 32;
    const _Float16* ap = a16 + (size_t)(m0 + sr) * EE + kh;
    const _Float16* bp = b16 + (size_t)(n0 + sr) * EE + kh;

    f32x4 acc[4][4];
#pragma unroll
    for (int a = 0; a < 4; ++a)
#pragma unroll
        for (int c = 0; c < 4; ++c) acc[a][c] = (f32x4){0.f, 0.f, 0.f, 0.f};

    for (int kc = 0; kc < 8; ++kc) {
#pragma unroll
        for (int q = 0; q < 4; ++q)
            *(f16x8*)&Al[sr * 72 + kh + q * 8] = *(const f16x8*)(ap + kc * 64 + q * 8);
#pragma unroll
        for (int q = 0; q < 4; ++q)
            *(f16x8*)&Bl[sr * 72 + kh + q * 8] = *(const f16x8*)(bp + kc * 64 + q * 8);
        __syncthreads();

#pragma unroll
        for (int kk = 0; kk < 2; ++kk) {
            f16x8 bfr[4];
#pragma unroll
            for (int nb = 0; nb < 4; ++nb)
                bfr[nb] = *(const f16x8*)&Bl[(nw * 64 + nb * 16 + n) * 72 + kk * 32 + quad * 8];
#pragma unroll
            for (int mb = 0; mb < 4; ++mb) {
                f16x8 afr = *(const f16x8*)&Al[(mw * 64 + mb * 16 + n) * 72 + kk * 32 + quad * 8];
#pragma unroll
                for (int nb = 0; nb < 4; ++nb)
                    acc[mb][nb] = __builtin_amdgcn_mfma_f32_16x16x32_f16(
                        afr, bfr[nb], acc[mb][nb], 0, 0, 0);
            }
        }
        __syncthreads();
    }

    int   cc[4];
    float bv[4];
#pragma unroll
    for (int nb = 0; nb < 4; ++nb) {
        cc[nb] = n0 + nw * 64 + nb * 16 + n;
        bv[nb] = bih[cc[nb]] + bhh[cc[nb]];
    }
#pragma unroll
    for (int mb = 0; mb < 4; ++mb) {
        int rowg = m0 + mw * 64 + mb * 16 + quad * 4;
#pragma unroll
        for (int nb = 0; nb < 4; ++nb) {
#pragma unroll
            for (int i = 0; i < 4; ++i)
                out[(size_t)(rowg + i) * HH + cc[nb]] = acc[mb][nb][i] + bv[nb];
        }
    }
}

// ---------------- Phase 1 fallback (no/small workspace): original f32 path.
__global__ __launch_bounds__(256, 3) void phase1(
    const int* __restrict__ idx, const float* __restrict__ emb,
    const float* __restrict__ Wih, const float* __restrict__ bih,
    const float* __restrict__ bhh, float* __restrict__ out) {
    __shared__ __align__(16) _Float16 Al[128 * 72];
    __shared__ __align__(16) _Float16 Bl[128 * 72];

    const int tid  = threadIdx.x;
    const int m0   = (blockIdx.x >> 2) * 128;
    const int n0   = (blockIdx.x & 3) * 128;
    const int wv   = tid >> 6;
    const int lane = tid & 63;
    const int n    = lane & 15;
    const int quad = lane >> 4;
    const int mw   = wv >> 1;
    const int nw   = wv & 1;

    const int sr = tid >> 1;
    const int kh = (tid & 1) * 32;
    const int rowidx = idx[m0 + sr];
    const float* ap = emb + (size_t)rowidx * EE + kh;
    const float* bp = Wih + (size_t)(n0 + sr) * EE + kh;

    f32x4 acc[4][4];
#pragma unroll
    for (int a = 0; a < 4; ++a)
#pragma unroll
        for (int c = 0; c < 4; ++c) acc[a][c] = (f32x4){0.f, 0.f, 0.f, 0.f};

    for (int kc = 0; kc < 8; ++kc) {
#pragma unroll
        for (int q = 0; q < 4; ++q) {
            float4 u = *(const float4*)(ap + kc * 64 + q * 8);
            float4 v = *(const float4*)(ap + kc * 64 + q * 8 + 4);
            *(f16x8*)&Al[sr * 72 + kh + q * 8] = pack8(u, v);
        }
#pragma unroll
        for (int q = 0; q < 4; ++q) {
            float4 u = *(const float4*)(bp + kc * 64 + q * 8);
            float4 v = *(const float4*)(bp + kc * 64 + q * 8 + 4);
            *(f16x8*)&Bl[sr * 72 + kh + q * 8] = pack8(u, v);
        }
        __syncthreads();

#pragma unroll
        for (int kk = 0; kk < 2; ++kk) {
            f16x8 bfr[4];
#pragma unroll
            for (int nb = 0; nb < 4; ++nb)
                bfr[nb] = *(const f16x8*)&Bl[(nw * 64 + nb * 16 + n) * 72 + kk * 32 + quad * 8];
#pragma unroll
            for (int mb = 0; mb < 4; ++mb) {
                f16x8 afr = *(const f16x8*)&Al[(mw * 64 + mb * 16 + n) * 72 + kk * 32 + quad * 8];
#pragma unroll
                for (int nb = 0; nb < 4; ++nb)
                    acc[mb][nb] = __builtin_amdgcn_mfma_f32_16x16x32_f16(
                        afr, bfr[nb], acc[mb][nb], 0, 0, 0);
            }
        }
        __syncthreads();
    }

    int   cc[4];
    float bv[4];
#pragma unroll
    for (int nb = 0; nb < 4; ++nb) {
        cc[nb] = n0 + nw * 64 + nb * 16 + n;
        bv[nb] = bih[cc[nb]] + bhh[cc[nb]];
    }
#pragma unroll
    for (int mb = 0; mb < 4; ++mb) {
        int rowg = m0 + mw * 64 + mb * 16 + quad * 4;
#pragma unroll
        for (int nb = 0; nb < 4; ++nb) {
#pragma unroll
            for (int i = 0; i < 4; ++i)
                out[(size_t)(rowg + i) * HH + cc[nb]] = acc[mb][nb][i] + bv[nb];
        }
    }
}

// ---------------- Phase 2 v3b: 64 WGs x 1 batch, own-kb software pipeline.
//  * 1 batch/WG: mfma count per WG is fixed by MxK coverage (256/step)
//    regardless of N-cols used -> halving batches/WG is free in matrix time
//    but halves the epilogue (1 h/thread) and uses 64 CUs.
//  * areg[mb][j]: j=0..6 <-> k-block (wv+1+j)&7, j=7 <-> own block (kb=wv).
//    Static register indexing (rule #20) with runtime global/LDS addresses.
//  * End of step: write own h bytes, read own 64B block of next h-image,
//    issue 4 MFMAs (C=0) BEFORE the barrier -> post-barrier phase starts
//    with the matrix pipe already fed while the 7 other reads drain.
//    (Wave-local LDS write->read is in-order; no barrier needed for it.)
//  * exp2-form epilogue: q = rint(127 - 254*rcp(exp2(z*inv2 + xp2)+1)),
//    h = fma(r,-2,1); the 2*log2e folds (xp2) precomputed at xp rotation.
//    exp2 via inline-asm v_exp_f32 (no builtin-availability risk).
//  * Raw `s_waitcnt lgkmcnt(0); s_barrier` (no vmcnt drain per step).
__global__ __launch_bounds__(512, 1) void phase2(
    const float* __restrict__ Whh, float* __restrict__ out) {
    __shared__ __align__(16) unsigned char himg[2][512];  // ping-pong i8 h[row]

    const int tid  = threadIdx.x;
    const int b    = blockIdx.x;        // one batch per WG
    const int wv   = tid >> 6;          // 0..7: W rows wv*64..+63
    const int lane = tid & 63;
    const int n    = lane & 15;
    const int quad = lane >> 4;

    // A-fragments (i8, 16x16x64), k-block order remapped per wave:
    // areg[mb][j] = W k-block (wv+1+j)&7 for j<7; areg[mb][7] = own (kb=wv).
    iv4 areg[4][8];
#pragma unroll
    for (int mb = 0; mb < 4; ++mb) {
        const float* wr = Whh + (size_t)(wv * 64 + mb * 16 + n) * HH + quad * 16;
#pragma unroll
        for (int j = 0; j < 8; ++j) {
            int kb = (j < 7) ? ((wv + 1 + j) & 7) : wv;
            const float4* p = (const float4*)(wr + kb * 64);
            iv4 v;
            v[0] = packw4(p[0]);
            v[1] = packw4(p[1]);
            v[2] = packw4(p[2]);
            v[3] = packw4(p[3]);
            areg[mb][j] = v;
        }
    }
    if (tid < 64) ((u64*)himg[0])[tid] = 0ull;   // h0 = 0 (512 B)
    __syncthreads();

    // Lane -> row bijection within the wave's 64 rows:
    // mb = (n>>2)&3, reg = n&3, row = wv*64 + mb*16 + quad*4 + reg.
    // (D[r=quad*4+reg][c=n]; every column holds the same z since the
    //  single-batch B-frag is replicated across all 16 columns.)
    const int  ilo = n & 1;
    const int  ihi = (n >> 1) & 1;
    const bool sb0 = ((n >> 2) & 1) != 0;
    const bool sb1 = ((n >> 3) & 1) != 0;
    const int  row = wv * 64 + ((n >> 2) & 3) * 16 + quad * 4 + (n & 3);
    float* obase = out + (size_t)b * (SS * HH) + row;

    int koff[7];
#pragma unroll
    for (int j = 0; j < 7; ++j) koff[j] = ((wv + 1 + j) & 7) * 64 + quad * 16;
    const int oown = wv * 64 + quad * 16;   // own block B-frag offset

    const float inv2 = (2.0f * 1.4426950408889634f) / (SW * 127.0f);
    const float K2   = 2.0f * 1.4426950408889634f;

    iv4 acc0 = (iv4){0,0,0,0}, acc1 = (iv4){0,0,0,0};
    iv4 acc2 = (iv4){0,0,0,0}, acc3 = (iv4){0,0,0,0};  // own-kb contrib of h0=0

    float xp2_c = obase[0] * K2;
    float xp2_n = obase[HH] * K2;
    float hl = 0.f;
    unsigned char* h0p = himg[0];
    unsigned char* h1p = himg[1];

    // HBR: buffer read this step; HNX: next buffer (write row byte + own read).
#define RNN_STEP(T, HBR, HNX)                                                  \
    {                                                                          \
        /* prefetch xp[T+2]; T+2==512..513 reads in-bounds garbage (unused):  */\
        /* max index 63*SS*HH+511+513*HH = 16778239 < BSH+BB*HH = 16809984 */  \
        float xp_f = obase[(size_t)((T) + 2) * HH];                            \
        _Pragma("unroll")                                                      \
        for (int j = 0; j < 7; ++j) {                                          \
            iv4 bfr = *(const iv4*)((HBR) + koff[j]);                          \
            acc0 = __builtin_amdgcn_mfma_i32_16x16x64_i8(areg[0][j], bfr, acc0, 0, 0, 0); \
            acc1 = __builtin_amdgcn_mfma_i32_16x16x64_i8(areg[1][j], bfr, acc1, 0, 0, 0); \
            acc2 = __builtin_amdgcn_mfma_i32_16x16x64_i8(areg[2][j], bfr, acc2, 0, 0, 0); \
            acc3 = __builtin_amdgcn_mfma_i32_16x16x64_i8(areg[3][j], bfr, acc3, 0, 0, 0); \
        }                                                                      \
        iv4 sa = sb0 ? acc1 : acc0;                                            \
        iv4 sc = sb0 ? acc3 : acc2;                                            \
        iv4 s  = sb1 ? sc : sa;                                                \
        int zA = ilo ? s[1] : s[0];                                            \
        int zB = ilo ? s[3] : s[2];                                            \
        int z  = ihi ? zB : zA;                                                \
        float u  = fmaf((float)z, inv2, xp2_c);                                \
        float ex;                                                              \
        __asm__("v_exp_f32 %0, %1" : "=v"(ex) : "v"(u));                       \
        float r  = __builtin_amdgcn_rcpf(ex + 1.0f);                           \
        int   q  = (int)rintf(fmaf(r, -254.0f, 127.0f));                       \
        *(char*)((HNX) + row) = (char)q;                                       \
        iv4 bown = *(const iv4*)((HNX) + oown);                                \
        acc0 = __builtin_amdgcn_mfma_i32_16x16x64_i8(areg[0][7], bown, (iv4){0,0,0,0}, 0, 0, 0); \
        acc1 = __builtin_amdgcn_mfma_i32_16x16x64_i8(areg[1][7], bown, (iv4){0,0,0,0}, 0, 0, 0); \
        acc2 = __builtin_amdgcn_mfma_i32_16x16x64_i8(areg[2][7], bown, (iv4){0,0,0,0}, 0, 0, 0); \
        acc3 = __builtin_amdgcn_mfma_i32_16x16x64_i8(areg[3][7], bown, (iv4){0,0,0,0}, 0, 0, 0); \
        float h = fmaf(r, -2.0f, 1.0f);                                        \
        obase[(size_t)(T) * HH] = h;                                           \
        hl = h;                                                                \
        __builtin_amdgcn_sched_barrier(0);                                     \
        __asm__ volatile("s_waitcnt lgkmcnt(0)\n\ts_barrier" ::: "memory");    \
        xp2_c = xp2_n; xp2_n = xp_f * K2;                                      \
    }

    for (int t = 0; t < SS; t += 2) {
        RNN_STEP(t,     h0p, h1p);
        RNN_STEP(t + 1, h1p, h0p);
    }
#undef RNN_STEP

    // final hidden state
    out[BSH + (size_t)b * HH + row] = hl;
}

extern "C" void kernel_launch(void* const* d_in, const int* in_sizes, int n_in,
                              void* d_out, int out_size, void* d_ws, size_t ws_size,
                              hipStream_t stream) {
    const int*   idx = (const int*)d_in[0];
    const float* emb = (const float*)d_in[1];
    const float* Wih = (const float*)d_in[2];
    const float* Whh = (const float*)d_in[3];
    const float* bih = (const float*)d_in[4];
    const float* bhh = (const float*)d_in[5];
    float* out = (float*)d_out;

    const size_t needA = (size_t)BB * SS * EE * sizeof(_Float16);  // 32 MB
    const size_t needB = (size_t)HH * EE * sizeof(_Float16);       // 0.5 MB
    if (d_ws && ws_size >= needA + needB) {
        _Float16* a16 = (_Float16*)d_ws;
        _Float16* b16 = (_Float16*)((char*)d_ws + needA);
        prep<<<dim3(8192 + 128), dim3(256), 0, stream>>>(idx, emb, Wih, a16, b16);
        phase1h<<<dim3(1024), dim3(256), 0, stream>>>(a16, b16, bih, bhh, out);
    } else {
        phase1<<<dim3(1024), dim3(256), 0, stream>>>(idx, emb, Wih, bih, bhh, out);
    }
    phase2<<<dim3(64), dim3(512), 0, stream>>>(Whh, out);
}